// Round 1
// baseline (265.636 us; speedup 1.0000x reference)
//
#include <hip/hip_runtime.h>

// DualRoPEAttention: x(2,2048,1024) fp32 -> QKV proj -> RoPE -> attention -> out proj.
// bf16 MFMA pipeline, fp32 accum/softmax. Round 0: correctness-first, reg-staged LDS.

typedef __attribute__((ext_vector_type(8))) short bf16x8;  // 8 bf16 = 4 VGPRs (MFMA A/B frag)
typedef __attribute__((ext_vector_type(4))) float f32x4;   // MFMA C/D frag
typedef unsigned short u16;
typedef unsigned int u32;

#define MFMA(a, b, c) __builtin_amdgcn_mfma_f32_16x16x32_bf16((a), (b), (c), 0, 0, 0)

__device__ __forceinline__ float bf2f(u16 u) {
  union { u32 i; float f; } v; v.i = ((u32)u) << 16; return v.f;
}
__device__ __forceinline__ u16 f2bf(float f) {  // round-to-nearest-even
  union { float f; u32 i; } v; v.f = f;
  u32 x = v.i;
  return (u16)((x + 0x7fffu + ((x >> 16) & 1u)) >> 16);
}

// ---------------- cast fp32 -> bf16 (8 elems/thread, vectorized) ----------------
__global__ __launch_bounds__(256) void cast_kernel(const float* __restrict__ in,
                                                   u16* __restrict__ out, int n8) {
  int i = blockIdx.x * 256 + threadIdx.x;
  if (i >= n8) return;
  const float4* p = (const float4*)in + 2 * (size_t)i;
  float4 a = p[0], b = p[1];
  bf16x8 o;
  o[0] = (short)f2bf(a.x); o[1] = (short)f2bf(a.y);
  o[2] = (short)f2bf(a.z); o[3] = (short)f2bf(a.w);
  o[4] = (short)f2bf(b.x); o[5] = (short)f2bf(b.y);
  o[6] = (short)f2bf(b.z); o[7] = (short)f2bf(b.w);
  *(bf16x8*)(out + 8 * (size_t)i) = o;
}

// ---------------- RoPE cos/sin table: [S=2048][P=32] ----------------
__global__ __launch_bounds__(256) void rope_table_kernel(float* __restrict__ cosT,
                                                         float* __restrict__ sinT) {
  int i = blockIdx.x * 256 + threadIdx.x;  // 65536
  int s = i >> 5, p = i & 31;
  float freq = powf(10000.0f, -(float)(2 * p) / 64.0f);
  float ang = (float)s * freq;
  cosT[i] = cosf(ang);
  sinT[i] = sinf(ang);
}

// ---------------- GEMM: C[M][Ntot] = A[M][1024] * Bt[n][k]^T (+bias) ----------------
// 128x128 tile, BK=64, 4 waves (2x2), 16x16x32 bf16 MFMA, XOR-swizzled LDS.
// !FINAL: QKV fused (Ntot=3072, Bt selected per n-tile), bf16 out.
// FINAL: out-proj (Ntot=1024), fp32 out + bias.
template <bool FINAL>
__global__ __launch_bounds__(256) void gemm_bt_kernel(
    const u16* __restrict__ A, const u16* __restrict__ B0, const u16* __restrict__ B1,
    const u16* __restrict__ B2, u16* __restrict__ Cb, float* __restrict__ Cf,
    const float* __restrict__ bias, int Ntot) {
  const int K = 1024;
  const int tid = threadIdx.x, lane = tid & 63, wid = tid >> 6;
  const int wr = wid >> 1, wc = wid & 1;
  const int m0 = blockIdx.y * 128;
  const int nt = blockIdx.x;
  const int n0 = nt * 128;
  const u16* Bt;
  int nloc0;
  if (!FINAL) {
    int sel = nt >> 3;
    Bt = sel == 0 ? B0 : (sel == 1 ? B1 : B2);
    nloc0 = n0 & 1023;
  } else {
    Bt = B0;
    nloc0 = n0;
  }

  __shared__ u16 As[128 * 64];
  __shared__ u16 Bs[128 * 64];

  f32x4 acc[4][4];
#pragma unroll
  for (int i = 0; i < 4; i++)
#pragma unroll
    for (int j = 0; j < 4; j++) acc[i][j] = f32x4{0.f, 0.f, 0.f, 0.f};

  bf16x8 sa[4], sb[4];
  const int e0 = tid * 8;

  auto loadstage = [&](int k0) {
#pragma unroll
    for (int p = 0; p < 4; ++p) {
      int e = p * 2048 + e0;
      int row = e >> 6, col = e & 63;
      sa[p] = *(const bf16x8*)(A + (size_t)(m0 + row) * K + k0 + col);
      sb[p] = *(const bf16x8*)(Bt + (size_t)(nloc0 + row) * K + k0 + col);
    }
  };
  auto writestage = [&]() {
#pragma unroll
    for (int p = 0; p < 4; ++p) {
      int e = p * 2048 + e0;
      int row = e >> 6, col = e & 63;
      int sc = col ^ ((row & 7) << 3);  // 16B-block XOR swizzle (T2)
      *(bf16x8*)(As + row * 64 + sc) = sa[p];
      *(bf16x8*)(Bs + row * 64 + sc) = sb[p];
    }
  };

  loadstage(0);
  for (int k0 = 0; k0 < K; k0 += 64) {
    __syncthreads();
    writestage();
    __syncthreads();
    if (k0 + 64 < K) loadstage(k0 + 64);  // prefetch next tile into regs
#pragma unroll
    for (int kk = 0; kk < 2; ++kk) {
      bf16x8 af[4], bfr[4];
#pragma unroll
      for (int i = 0; i < 4; ++i) {
        int row = wr * 64 + i * 16 + (lane & 15);
        int col = (kk * 32 + (lane >> 4) * 8) ^ ((row & 7) << 3);
        af[i] = *(const bf16x8*)(As + row * 64 + col);
      }
#pragma unroll
      for (int j = 0; j < 4; ++j) {
        int row = wc * 64 + j * 16 + (lane & 15);
        int col = (kk * 32 + (lane >> 4) * 8) ^ ((row & 7) << 3);
        bfr[j] = *(const bf16x8*)(Bs + row * 64 + col);
      }
#pragma unroll
      for (int i = 0; i < 4; ++i)
#pragma unroll
        for (int j = 0; j < 4; ++j) acc[i][j] = MFMA(af[i], bfr[j], acc[i][j]);
    }
  }

#pragma unroll
  for (int i = 0; i < 4; ++i)
#pragma unroll
    for (int j = 0; j < 4; ++j)
#pragma unroll
      for (int r = 0; r < 4; ++r) {
        // C/D layout: col = lane&15, row = (lane>>4)*4 + r  [measured m89/m91]
        int row = m0 + wr * 64 + i * 16 + (lane >> 4) * 4 + r;
        int col = n0 + wc * 64 + j * 16 + (lane & 15);
        if (FINAL)
          Cf[(size_t)row * Ntot + col] = acc[i][j][r] + bias[col];
        else
          Cb[(size_t)row * Ntot + col] = f2bf(acc[i][j][r]);
      }
}

// ---------------- RoPE apply: C[4096][3072] -> q,k [32][2048][64] bf16 ----------------
// Folds 1/sqrt(D)=0.125 into q.
__global__ __launch_bounds__(256) void rope_apply_kernel(
    const u16* __restrict__ C, const float* __restrict__ cosT, const float* __restrict__ sinT,
    u16* __restrict__ Qo, u16* __restrict__ Ko) {
  int idx = blockIdx.x * 256 + threadIdx.x;  // 2M = 4096*16*32
  int p = idx & 31, h = (idx >> 5) & 15, m = idx >> 9;
  int s = m & 2047, b = m >> 11;
  float c = cosT[s * 32 + p], sn = sinT[s * 32 + p];
  size_t src = (size_t)m * 3072 + h * 64 + 2 * p;
  u32 qu = *(const u32*)(C + src);
  u32 ku = *(const u32*)(C + src + 1024);
  float q0 = bf2f((u16)qu), q1 = bf2f((u16)(qu >> 16));
  float k0 = bf2f((u16)ku), k1 = bf2f((u16)(ku >> 16));
  float qr0 = (q0 * c - q1 * sn) * 0.125f;
  float qr1 = (q0 * sn + q1 * c) * 0.125f;
  float kr0 = k0 * c - k1 * sn;
  float kr1 = k0 * sn + k1 * c;
  size_t dst = ((size_t)(b * 16 + h) * 2048 + s) * 64 + 2 * p;
  *(u32*)(Qo + dst) = (u32)f2bf(qr0) | ((u32)f2bf(qr1) << 16);
  *(u32*)(Ko + dst) = (u32)f2bf(kr0) | ((u32)f2bf(kr1) << 16);
}

// ---------------- V transpose: C v-region [4096][3072] -> VT [32][64][2048] ----------------
__global__ __launch_bounds__(256) void transpose_v_kernel(const u16* __restrict__ C,
                                                          u16* __restrict__ VT) {
  int st = blockIdx.x, bh = blockIdx.y;
  int b = bh >> 4, h = bh & 15;
  __shared__ u16 tile[64][72];  // +8 pad (144B row = 9*16B, keeps 16B alignment)
  int t = threadIdx.x;
#pragma unroll
  for (int p = 0; p < 2; ++p) {
    int r = p * 32 + (t >> 3), cb = (t & 7) * 8;
    bf16x8 v = *(const bf16x8*)(C + (size_t)(b * 2048 + st * 64 + r) * 3072 + 2048 + h * 64 + cb);
    *(bf16x8*)(&tile[r][cb]) = v;
  }
  __syncthreads();
#pragma unroll
  for (int p = 0; p < 2; ++p) {
    int d = p * 32 + (t >> 3), sb = (t & 7) * 8;
    bf16x8 v;
#pragma unroll
    for (int j = 0; j < 8; ++j) v[j] = (short)tile[sb + j][d];
    *(bf16x8*)(VT + ((size_t)bh * 64 + d) * 2048 + st * 64 + sb) = v;
  }
}

// ---------------- Flash attention ----------------
// Grid (qt=32, bh=32), 256 threads = 4 waves; wave owns 16 q rows; KVBLK=64.
// Q pre-scaled by 0.125. Online softmax in fp32. P via per-wave swizzled LDS.
__global__ __launch_bounds__(256) void attn_kernel(
    const u16* __restrict__ Q, const u16* __restrict__ Kk, const u16* __restrict__ VT,
    u16* __restrict__ O) {
  const int qt = blockIdx.x, bh = blockIdx.y;
  const int tid = threadIdx.x, lane = tid & 63, wid = tid >> 6;
  const int b = bh >> 4, h = bh & 15;

  __shared__ u16 Ks[64 * 64];     // [kv][d], swizzled
  __shared__ u16 Vs[64 * 64];     // [d][kv], swizzled
  __shared__ u16 Ps[4][16 * 64];  // per-wave P, swizzled

  // Q A-frags: row = lane&15 (q row), k = d = (lane>>4)*8 + j
  const int qrow = qt * 64 + wid * 16 + (lane & 15);
  const size_t qbase = ((size_t)bh * 2048 + qrow) * 64;
  bf16x8 qf[2];
  qf[0] = *(const bf16x8*)(Q + qbase + (lane >> 4) * 8);
  qf[1] = *(const bf16x8*)(Q + qbase + 32 + (lane >> 4) * 8);

  f32x4 o[4];
#pragma unroll
  for (int j = 0; j < 4; ++j) o[j] = f32x4{0.f, 0.f, 0.f, 0.f};
  float mrun[4] = {-1e30f, -1e30f, -1e30f, -1e30f};
  float lrun[4] = {0.f, 0.f, 0.f, 0.f};

  const size_t kbase = (size_t)bh * 2048 * 64;
  const size_t vbase = (size_t)bh * 64 * 2048;

  bf16x8 sk[2], sv[2];
  auto loadstage = [&](int t) {
#pragma unroll
    for (int p = 0; p < 2; ++p) {
      int e = p * 2048 + tid * 8;
      int row = e >> 6, col = e & 63;
      sk[p] = *(const bf16x8*)(Kk + kbase + (size_t)(t * 64 + row) * 64 + col);
      sv[p] = *(const bf16x8*)(VT + vbase + (size_t)row * 2048 + t * 64 + col);
    }
  };
  auto writestage = [&]() {
#pragma unroll
    for (int p = 0; p < 2; ++p) {
      int e = p * 2048 + tid * 8;
      int row = e >> 6, col = e & 63;
      int sc = col ^ ((row & 7) << 3);
      *(bf16x8*)(Ks + row * 64 + sc) = sk[p];
      *(bf16x8*)(Vs + row * 64 + sc) = sv[p];
    }
  };

  loadstage(0);
  for (int t = 0; t < 32; ++t) {
    __syncthreads();
    writestage();
    __syncthreads();
    if (t + 1 < 32) loadstage(t + 1);

    // S = Q K^T  (B-frag: col = key = lane&15, k = d contiguous 8)
    f32x4 sc4[4];
#pragma unroll
    for (int j = 0; j < 4; ++j) sc4[j] = f32x4{0.f, 0.f, 0.f, 0.f};
#pragma unroll
    for (int kk = 0; kk < 2; ++kk) {
      bf16x8 kf[4];
#pragma unroll
      for (int j = 0; j < 4; ++j) {
        int row = j * 16 + (lane & 15);
        int col = (kk * 32 + (lane >> 4) * 8) ^ ((row & 7) << 3);
        kf[j] = *(const bf16x8*)(Ks + row * 64 + col);
      }
#pragma unroll
      for (int j = 0; j < 4; ++j) sc4[j] = MFMA(qf[kk], kf[j], sc4[j]);
    }

    // online softmax (rows = (lane>>4)*4 + r; 16 lanes share rows)
    float mnew[4], corr[4], rsum[4];
#pragma unroll
    for (int r = 0; r < 4; ++r) {
      float mx = fmaxf(fmaxf(sc4[0][r], sc4[1][r]), fmaxf(sc4[2][r], sc4[3][r]));
#pragma unroll
      for (int d = 1; d < 16; d <<= 1) mx = fmaxf(mx, __shfl_xor(mx, d, 64));
      mnew[r] = fmaxf(mrun[r], mx);
      corr[r] = __expf(mrun[r] - mnew[r]);
      mrun[r] = mnew[r];
      rsum[r] = 0.f;
    }
#pragma unroll
    for (int j = 0; j < 4; ++j)
#pragma unroll
      for (int r = 0; r < 4; ++r) {
        float pv = __expf(sc4[j][r] - mnew[r]);
        sc4[j][r] = pv;
        rsum[r] += pv;
      }
#pragma unroll
    for (int r = 0; r < 4; ++r) {
#pragma unroll
      for (int d = 1; d < 16; d <<= 1) rsum[r] += __shfl_xor(rsum[r], d, 64);
      lrun[r] = lrun[r] * corr[r] + rsum[r];
    }
#pragma unroll
    for (int j = 0; j < 4; ++j) {
      f32x4 t4 = o[j];
      t4[0] *= corr[0]; t4[1] *= corr[1]; t4[2] *= corr[2]; t4[3] *= corr[3];
      o[j] = t4;
    }

    // P -> per-wave LDS (swizzled scalar writes), then A-frag reads
    char* Pw = (char*)&Ps[wid][0];
#pragma unroll
    for (int j = 0; j < 4; ++j)
#pragma unroll
      for (int r = 0; r < 4; ++r) {
        int prow = (lane >> 4) * 4 + r, pcol = j * 16 + (lane & 15);
        int off = (prow * 128 + pcol * 2) ^ ((prow & 7) << 4);
        *(u16*)(Pw + off) = f2bf(sc4[j][r]);
      }

    // PV: A = P (row=q=lane&15, k=kv), B = V (col=d=lane&15, k=kv) from VT layout
#pragma unroll
    for (int kk = 0; kk < 2; ++kk) {
      int prow = lane & 15;
      int poff = (prow * 128 + (kk * 32 + (lane >> 4) * 8) * 2) ^ ((prow & 7) << 4);
      bf16x8 pf = *(const bf16x8*)(Pw + poff);
      bf16x8 vf[4];
#pragma unroll
      for (int j = 0; j < 4; ++j) {
        int vrow = j * 16 + (lane & 15);
        int vcol = (kk * 32 + (lane >> 4) * 8) ^ ((vrow & 7) << 3);
        vf[j] = *(const bf16x8*)(Vs + vrow * 64 + vcol);
      }
#pragma unroll
      for (int j = 0; j < 4; ++j) o[j] = MFMA(pf, vf[j], o[j]);
    }
  }

  // epilogue: O[b,s,h,d] -> [4096][1024] bf16
#pragma unroll
  for (int j = 0; j < 4; ++j)
#pragma unroll
    for (int r = 0; r < 4; ++r) {
      int srow = qt * 64 + wid * 16 + (lane >> 4) * 4 + r;
      int col = h * 64 + j * 16 + (lane & 15);
      float val = o[j][r] / lrun[r];
      O[(size_t)(b * 2048 + srow) * 1024 + col] = f2bf(val);
    }
}

// ---------------- launch ----------------
extern "C" void kernel_launch(void* const* d_in, const int* in_sizes, int n_in,
                              void* d_out, int out_size, void* d_ws, size_t ws_size,
                              hipStream_t stream) {
  const float* x = (const float*)d_in[0];
  const float* Wq = (const float*)d_in[1];
  const float* Wk = (const float*)d_in[2];
  const float* Wv = (const float*)d_in[3];
  const float* Wo = (const float*)d_in[4];
  const float* bo = (const float*)d_in[5];

  char* ws = (char*)d_ws;
  size_t off = 0;
  auto carve = [&](size_t bytes) {
    void* pp = ws + off;
    off += (bytes + 255) & ~(size_t)255;
    return pp;
  };
  u16* xb = (u16*)carve(4194304ull * 2);
  u16* Wqb = (u16*)carve(1048576ull * 2);
  u16* Wkb = (u16*)carve(1048576ull * 2);
  u16* Wvb = (u16*)carve(1048576ull * 2);
  u16* Wob = (u16*)carve(1048576ull * 2);
  float* cosT = (float*)carve(65536ull * 4);
  float* sinT = (float*)carve(65536ull * 4);
  u16* Cqkv = (u16*)carve(4096ull * 3072 * 2);
  u16* q_r = (u16*)carve(4194304ull * 2);
  u16* k_r = (u16*)carve(4194304ull * 2);
  u16* vT = (u16*)carve(4194304ull * 2);
  u16* attn_out = Cqkv;  // reuse: C consumed by rope/transpose before attention

  cast_kernel<<<2048, 256, 0, stream>>>(x, xb, 524288);
  cast_kernel<<<512, 256, 0, stream>>>(Wq, Wqb, 131072);
  cast_kernel<<<512, 256, 0, stream>>>(Wk, Wkb, 131072);
  cast_kernel<<<512, 256, 0, stream>>>(Wv, Wvb, 131072);
  cast_kernel<<<512, 256, 0, stream>>>(Wo, Wob, 131072);
  rope_table_kernel<<<256, 256, 0, stream>>>(cosT, sinT);

  gemm_bt_kernel<false><<<dim3(24, 32), 256, 0, stream>>>(xb, Wqb, Wkb, Wvb, Cqkv, nullptr,
                                                          nullptr, 3072);
  rope_apply_kernel<<<8192, 256, 0, stream>>>(Cqkv, cosT, sinT, q_r, k_r);
  transpose_v_kernel<<<dim3(32, 32), 256, 0, stream>>>(Cqkv, vT);
  attn_kernel<<<dim3(32, 32), 256, 0, stream>>>(q_r, k_r, vT, attn_out);
  gemm_bt_kernel<true><<<dim3(8, 32), 256, 0, stream>>>(attn_out, Wob, nullptr, nullptr, nullptr,
                                                        (float*)d_out, bo, 1024);
}